// Round 6
// baseline (206.956 us; speedup 1.0000x reference)
//
#include <hip/hip_runtime.h>
#include <stdint.h>

#define S_LEN 2048
#define D_MODEL 1024
#define NH 16
#define DKV 64

typedef unsigned short u16;
typedef __bf16 bf16x8 __attribute__((ext_vector_type(8)));
typedef float f32x4 __attribute__((ext_vector_type(4)));
typedef float f32x16 __attribute__((ext_vector_type(16)));

__device__ __forceinline__ u16 f2bf(float f) {
  union { float f; uint32_t u; } v; v.f = f;
  uint32_t r = v.u + 0x7FFFu + ((v.u >> 16) & 1u);
  return (u16)(r >> 16);
}
// pack two positive floats to bf16x2 (cheap round; softmax-normalized later)
__device__ __forceinline__ uint32_t pkbf(float lo, float hi) {
  union { float f; uint32_t u; } a, b; a.f = lo; b.f = hi;
  return ((b.u + 0x8000u) & 0xFFFF0000u) | ((a.u + 0x8000u) >> 16);
}
// async global->LDS 16B: per-wave, dest = wave-uniform base + lane*16
__device__ __forceinline__ void gl16(const u16* g, u16* l) {
  __builtin_amdgcn_global_load_lds(
      (const __attribute__((address_space(1))) unsigned int*)g,
      (__attribute__((address_space(3))) unsigned int*)l, 16, 0, 0);
}

// ---------- convert Q,K,V fp32 -> bf16 ----------
__global__ __launch_bounds__(256) void conv_qkv_k(
    const float* __restrict__ Q, const float* __restrict__ K,
    const float* __restrict__ V, u16* __restrict__ out) {
  const float* src = (blockIdx.z == 0) ? Q : (blockIdx.z == 1) ? K : V;
  u16* dst = out + (size_t)blockIdx.z * S_LEN * D_MODEL;
  size_t i = ((size_t)blockIdx.x * blockDim.x + threadIdx.x) * 4;
  const float4 v = *(const float4*)(src + i);
  union { u16 h[4]; uint2 u2; } o;
  o.h[0] = f2bf(v.x); o.h[1] = f2bf(v.y); o.h[2] = f2bf(v.z); o.h[3] = f2bf(v.w);
  *(uint2*)(dst + i) = o.u2;
}

// ---------- transpose+convert Wq/Wk/Wv: [D][DK] -> [DK][D] per head ----------
__global__ __launch_bounds__(256) void transpose_qkvw_k(
    const float* __restrict__ Wq, const float* __restrict__ Wk,
    const float* __restrict__ Wv, u16* __restrict__ Wqt,
    u16* __restrict__ Wkt, u16* __restrict__ Wvt) {
  __shared__ float tile[32][33];
  const int which = blockIdx.z >> 4, head = blockIdx.z & 15;
  const float* ip = ((which == 0) ? Wq : (which == 1) ? Wk : Wv) + (size_t)head * D_MODEL * DKV;
  u16* op = ((which == 0) ? Wqt : (which == 1) ? Wkt : Wvt) + (size_t)head * D_MODEL * DKV;
  int r0 = blockIdx.y * 32, c0 = blockIdx.x * 32;
  int tr = threadIdx.x >> 5, tc = threadIdx.x & 31;
#pragma unroll
  for (int i = 0; i < 4; i++)
    tile[tr + i * 8][tc] = ip[(size_t)(r0 + tr + i * 8) * DKV + c0 + tc];
  __syncthreads();
#pragma unroll
  for (int i = 0; i < 4; i++) {
    int c = tr + i * 8;
    op[(size_t)(c0 + c) * D_MODEL + r0 + tc] = f2bf(tile[tc][c]);
  }
}

// ---------- transpose + convert generic (Wo): fp32 [R][C] -> bf16 [C][R] ----------
__global__ __launch_bounds__(256) void transpose_conv_k(
    const float* __restrict__ in, u16* __restrict__ out, int R, int C) {
  __shared__ float tile[32][33];
  int r0 = blockIdx.y * 32, c0 = blockIdx.x * 32;
  int tr = threadIdx.x >> 5, tc = threadIdx.x & 31;
#pragma unroll
  for (int i = 0; i < 4; i++)
    tile[tr + i * 8][tc] = in[(size_t)(r0 + tr + i * 8) * C + c0 + tc];
  __syncthreads();
#pragma unroll
  for (int i = 0; i < 4; i++) {
    int c = tr + i * 8;
    out[(size_t)(c0 + c) * R + r0 + tc] = f2bf(tile[tc][c]);
  }
}

// ---------- projection GEMM m97-style: 128x128 tile, BK=64, async dbuf, 1 barrier/iter ----------
__global__ __launch_bounds__(256, 2) void proj_gemm_k(
    const u16* __restrict__ qkvb, const u16* __restrict__ Wqt,
    const u16* __restrict__ Wkt, const u16* __restrict__ Wvt,
    const float* __restrict__ bq, const float* __restrict__ bk,
    const float* __restrict__ bv,
    u16* __restrict__ qb, u16* __restrict__ kb, u16* __restrict__ vT) {
  const int z = blockIdx.z;
  const int m0 = blockIdx.x * 128, n0 = blockIdx.y * 128;
  const u16* A = qkvb + (size_t)z * S_LEN * D_MODEL;
  const u16* Bt = (z == 0) ? Wqt : (z == 1) ? Wkt : Wvt;
  const float* bias = (z == 0) ? bq : (z == 1) ? bk : bv;
  const float scale = (z == 0) ? 0.18033688f : 1.0f;  // (1/8)*log2(e) folded into q

  __shared__ __align__(16) u16 smem[4 * 8192];  // A0 A1 B0 B1 (16KB each)
  const int tid = threadIdx.x;
  const int w = tid >> 6, lane = tid & 63, quad = lane >> 4, l15 = lane & 15;
  const int wm = (w >> 1) * 64, wn = (w & 1) * 64;
  const int pb = w * 256;

  f32x4 acc[4][4] = {};

  {
    u16* As = smem; u16* Bs = smem + 16384;
#pragma unroll
    for (int e = 0; e < 4; e++) {
      int p = pb + e * 64 + lane;
      int r = p >> 3, cg = (p & 7) ^ (r & 7);
      gl16(&A[(size_t)(m0 + r) * D_MODEL + cg * 8], As + (pb + e * 64) * 8);
      gl16(&Bt[(size_t)(n0 + r) * D_MODEL + cg * 8], Bs + (pb + e * 64) * 8);
    }
  }
  for (int it = 0; it < 16; it++) {
    __syncthreads();
    if (it < 15) {
      const int k0 = (it + 1) * 64;
      u16* As = smem + ((it + 1) & 1) * 8192;
      u16* Bs = smem + 16384 + ((it + 1) & 1) * 8192;
#pragma unroll
      for (int e = 0; e < 4; e++) {
        int p = pb + e * 64 + lane;
        int r = p >> 3, cg = (p & 7) ^ (r & 7);
        gl16(&A[(size_t)(m0 + r) * D_MODEL + k0 + cg * 8], As + (pb + e * 64) * 8);
        gl16(&Bt[(size_t)(n0 + r) * D_MODEL + k0 + cg * 8], Bs + (pb + e * 64) * 8);
      }
    }
    const u16* As = smem + (it & 1) * 8192;
    const u16* Bs = smem + 16384 + (it & 1) * 8192;
#pragma unroll
    for (int kc = 0; kc < 2; kc++) {
      bf16x8 af[4], bfr[4];
      const int c = kc * 4 + quad;
#pragma unroll
      for (int t = 0; t < 4; t++) {
        int ma = wm + t * 16 + l15, na = wn + t * 16 + l15;
        af[t] = *(const bf16x8*)&As[(ma * 8 + (c ^ (ma & 7))) * 8];
        bfr[t] = *(const bf16x8*)&Bs[(na * 8 + (c ^ (na & 7))) * 8];
      }
#pragma unroll
      for (int tm = 0; tm < 4; tm++)
#pragma unroll
        for (int tn = 0; tn < 4; tn++)
          acc[tm][tn] = __builtin_amdgcn_mfma_f32_16x16x32_bf16(af[tm], bfr[tn], acc[tm][tn], 0, 0, 0);
    }
  }

  if (z < 2) {
    u16* O = (z == 0) ? qb : kb;
#pragma unroll
    for (int tm = 0; tm < 4; tm++)
#pragma unroll
      for (int tn = 0; tn < 4; tn++)
#pragma unroll
        for (int r = 0; r < 4; r++) {
          int row = m0 + wm + tm * 16 + quad * 4 + r;
          int col = n0 + wn + tn * 16 + l15;
          O[(size_t)row * D_MODEL + col] = f2bf((acc[tm][tn][r] + bias[col]) * scale);
        }
  } else {
#pragma unroll
    for (int tm = 0; tm < 4; tm++)
#pragma unroll
      for (int tn = 0; tn < 4; tn++) {
        int col = n0 + wn + tn * 16 + l15;
        int row0 = m0 + wm + tm * 16 + quad * 4;
        float b = bias[col];
        union { u16 h[4]; uint2 u2; } o;
#pragma unroll
        for (int r = 0; r < 4; r++) o.h[r] = f2bf(acc[tm][tn][r] + b);
        *(uint2*)&vT[(size_t)col * S_LEN + row0] = o.u2;
      }
  }
}

// ---------- attention: 32x32x16 MFMA compute + plain-load 2-barrier staging ----------
// 512 thr = 8 waves = {2 q-subs(32q)} x {4 t-subs(32t)}; q-tile 64, t-tile 128.
// Sᵀ = K·Qᵀ; P C-layout -> A-layout via per-wave LDS strip (packed b64 writes);
// partials combined with LDS float atomics. p = exp2(s) (log2e folded into q).
__global__ __launch_bounds__(512, 4) void attn_k(
    const u16* __restrict__ qb, const u16* __restrict__ kb,
    const u16* __restrict__ vT, u16* __restrict__ conc) {
  const int h = blockIdx.y, qblk = blockIdx.x * 64;
  const int tid = threadIdx.x;
  const int w = tid >> 6, lane = tid & 63;
  const int l31 = lane & 31, h5 = lane >> 5;
  const int qsub = w & 1, tsub = w >> 1;
  const int q0 = qblk + qsub * 32;

  __shared__ __align__(16) u16 Ks[128 * 72];   // K tile [t 128][dk 64] pad->72 (18KB)
  __shared__ __align__(16) u16 Vs[64 * 136];   // Vᵀ tile [dv 64][t 128] pad->136 (17KB)
  __shared__ __align__(16) u16 Ps[8 * 1024];   // per-wave P strip (16KB)
  u16* Pw = &Ps[w * 1024];

  const u16* kbase = kb + (size_t)h * 64;
  const u16* vbase = vT + (size_t)(h * 64) * S_LEN;

  // Q B-frags: B[k=dk][n=q]; k = kI*16 + h5*8 + j  (layout HW-verified in r5)
  bf16x8 qf[4];
#pragma unroll
  for (int kI = 0; kI < 4; kI++)
    qf[kI] = *(const bf16x8*)&qb[(size_t)(q0 + l31) * D_MODEL + h * 64 + kI * 16 + h5 * 8];

  f32x16 oacc[2] = {};
  float lsum = 0.f;

  for (int it = 0; it < 16; it++) {
    const int t0 = it * 128;
    // plain vectorized staging: K natural rows, Vᵀ rows; 4 int4 per thread
#pragma unroll
    for (int j = 0; j < 2; j++) {
      int p = j * 512 + tid;  // 0..1023 chunks of 16B
      int kt = p >> 3, kc = p & 7;
      *(int4*)&Ks[kt * 72 + kc * 8] = *(const int4*)&kbase[(size_t)(t0 + kt) * D_MODEL + kc * 8];
      int dv = p >> 4, ct = p & 15;
      *(int4*)&Vs[dv * 136 + ct * 8] = *(const int4*)&vbase[(size_t)dv * S_LEN + t0 + ct * 8];
    }
    __syncthreads();

    // Sᵀ[t 32][q 32]: A = K rows (wave's t-sub), B = Q
    f32x16 sacc = {};
#pragma unroll
    for (int kI = 0; kI < 4; kI++) {
      bf16x8 ka = *(const bf16x8*)&Ks[(tsub * 32 + l31) * 72 + kI * 16 + h5 * 8];
      sacc = __builtin_amdgcn_mfma_f32_32x32x16_bf16(ka, qf[kI], sacc, 0, 0, 0);
    }
    // p = 2^s; C row t_local = (reg&3)+8*(reg>>2)+4*h5, col q=l31 -> packed b64 P writes
#pragma unroll
    for (int g = 0; g < 4; g++) {
      float p0 = exp2f(sacc[4 * g + 0]);
      float p1 = exp2f(sacc[4 * g + 1]);
      float p2 = exp2f(sacc[4 * g + 2]);
      float p3 = exp2f(sacc[4 * g + 3]);
      lsum += (p0 + p1) + (p2 + p3);
      uint2 pw2; pw2.x = pkbf(p0, p1); pw2.y = pkbf(p2, p3);
      *(uint2*)&Pw[(g * 32 + l31) * 8 + h5 * 4] = pw2;
    }
    // O += P·V : A = P[q][t_local] (wave strip), B = Vᵀ rows (k = wave's t strip)
#pragma unroll
    for (int kI2 = 0; kI2 < 2; kI2++) {
      bf16x8 pa = *(const bf16x8*)&Pw[((kI2 * 2 + h5) * 32 + l31) * 8];
#pragma unroll
      for (int d = 0; d < 2; d++) {
        bf16x8 vb = *(const bf16x8*)&Vs[(d * 32 + l31) * 136 + tsub * 32 + kI2 * 16 + h5 * 8];
        oacc[d] = __builtin_amdgcn_mfma_f32_32x32x16_bf16(pa, vb, oacc[d], 0, 0, 0);
      }
    }
    __syncthreads();
  }

  // combine 8 waves' partials in LDS (overlay Ks/Vs — loop fully done)
  float* Of = (float*)Ks;   // [64 q][64 dv] = 16KB
  float* lf = (float*)Vs;   // [64 q]
#pragma unroll
  for (int j = 0; j < 8; j++) Of[tid * 8 + j] = 0.f;
  if (tid < 64) lf[tid] = 0.f;
  __syncthreads();
#pragma unroll
  for (int d = 0; d < 2; d++)
#pragma unroll
    for (int reg = 0; reg < 16; reg++) {
      int qq = qsub * 32 + (reg & 3) + 8 * (reg >> 2) + 4 * h5;
      atomicAdd(&Of[qq * 64 + d * 32 + l31], oacc[d][reg]);
    }
  atomicAdd(&lf[qsub * 32 + l31], lsum);
  __syncthreads();

  const int q = tid >> 3, dv0 = (tid & 7) * 8;
  float li = 1.0f / lf[q];
  union { u16 hh[8]; uint4 u4; } o;
#pragma unroll
  for (int j = 0; j < 8; j++) o.hh[j] = f2bf(Of[q * 64 + dv0 + j] * li);
  *(uint4*)&conc[(size_t)(qblk + q) * D_MODEL + h * 64 + dv0] = o.u4;
}

// ---------- output GEMM: 64x64 tile, BK=64, async dbuf, 1 barrier/iter ----------
__global__ __launch_bounds__(256, 4) void out_gemm_k(
    const u16* __restrict__ A, const u16* __restrict__ Bt,
    const float* __restrict__ bias, float* __restrict__ out) {
  const int n0 = blockIdx.x * 64, m0 = blockIdx.y * 64;
  __shared__ __align__(16) u16 smem[4 * 4096];  // A0 A1 B0 B1 (8KB each)
  const int tid = threadIdx.x;
  const int w = tid >> 6, lane = tid & 63, quad = lane >> 4, l15 = lane & 15;
  const int wm = (w >> 1) * 32, wn = (w & 1) * 32;
  const int pb = w * 128;

  f32x4 acc[2][2] = {};
  {
    u16* As = smem; u16* Bs = smem + 8192;
#pragma unroll
    for (int e = 0; e < 2; e++) {
      int p = pb + e * 64 + lane;
      int r = p >> 3, cg = (p & 7) ^ (r & 7);
      gl16(&A[(size_t)(m0 + r) * D_MODEL + cg * 8], As + (pb + e * 64) * 8);
      gl16(&Bt[(size_t)(n0 + r) * D_MODEL + cg * 8], Bs + (pb + e * 64) * 8);
    }
  }
  for (int it = 0; it < 16; it++) {
    __syncthreads();
    if (it < 15) {
      const int k0 = (it + 1) * 64;
      u16* As = smem + ((it + 1) & 1) * 4096;
      u16* Bs = smem + 8192 + ((it + 1) & 1) * 4096;
#pragma unroll
      for (int e = 0; e < 2; e++) {
        int p = pb + e * 64 + lane;
        int r = p >> 3, cg = (p & 7) ^ (r & 7);
        gl16(&A[(size_t)(m0 + r) * D_MODEL + k0 + cg * 8], As + (pb + e * 64) * 8);
        gl16(&Bt[(size_t)(n0 + r) * D_MODEL + k0 + cg * 8], Bs + (pb + e * 64) * 8);
      }
    }
    const u16* As = smem + (it & 1) * 4096;
    const u16* Bs = smem + 8192 + (it & 1) * 4096;
#pragma unroll
    for (int kc = 0; kc < 2; kc++) {
      const int c = kc * 4 + quad;
      bf16x8 af[2], bfr[2];
#pragma unroll
      for (int t = 0; t < 2; t++) {
        int ma = wm + t * 16 + l15, na = wn + t * 16 + l15;
        af[t] = *(const bf16x8*)&As[(ma * 8 + (c ^ (ma & 7))) * 8];
        bfr[t] = *(const bf16x8*)&Bs[(na * 8 + (c ^ (na & 7))) * 8];
      }
#pragma unroll
      for (int tm = 0; tm < 2; tm++)
#pragma unroll
        for (int tn = 0; tn < 2; tn++)
          acc[tm][tn] = __builtin_amdgcn_mfma_f32_16x16x32_bf16(af[tm], bfr[tn], acc[tm][tn], 0, 0, 0);
    }
  }
#pragma unroll
  for (int tm = 0; tm < 2; tm++)
#pragma unroll
    for (int tn = 0; tn < 2; tn++)
#pragma unroll
      for (int r = 0; r < 4; r++) {
        int row = m0 + wm + tm * 16 + quad * 4 + r;
        int col = n0 + wn + tn * 16 + l15;
        out[(size_t)row * D_MODEL + col] = acc[tm][tn][r] + bias[col];
      }
}

extern "C" void kernel_launch(void* const* d_in, const int* in_sizes, int n_in,
                              void* d_out, int out_size, void* d_ws, size_t ws_size,
                              hipStream_t stream) {
  const float* Q  = (const float*)d_in[0];
  const float* K  = (const float*)d_in[1];
  const float* V  = (const float*)d_in[2];
  const float* Wq = (const float*)d_in[3];
  const float* bq = (const float*)d_in[4];
  const float* Wk = (const float*)d_in[5];
  const float* bk = (const float*)d_in[6];
  const float* Wv = (const float*)d_in[7];
  const float* bv = (const float*)d_in[8];
  const float* Wo = (const float*)d_in[9];
  const float* bo = (const float*)d_in[10];
  float* out = (float*)d_out;

  u16* ws = (u16*)d_ws;
  u16* QKVb = ws;                                   // 3*S*D
  u16* Wqt  = QKVb + (size_t)3 * S_LEN * D_MODEL;   // D*D each
  u16* Wkt  = Wqt + (size_t)D_MODEL * D_MODEL;
  u16* Wvt  = Wkt + (size_t)D_MODEL * D_MODEL;
  u16* Wot  = Wvt + (size_t)D_MODEL * D_MODEL;
  u16* qbuf = Wot + (size_t)D_MODEL * D_MODEL;      // S*D
  u16* kbuf = qbuf + (size_t)S_LEN * D_MODEL;       // S*D
  u16* vTb  = kbuf + (size_t)S_LEN * D_MODEL;       // D*S
  u16* conc = vTb + (size_t)S_LEN * D_MODEL;        // S*D

  conv_qkv_k<<<dim3(S_LEN * D_MODEL / 1024, 1, 3), 256, 0, stream>>>(Q, K, V, QKVb);
  transpose_qkvw_k<<<dim3(DKV / 32, D_MODEL / 32, NH * 3), 256, 0, stream>>>(
      Wq, Wk, Wv, Wqt, Wkt, Wvt);
  transpose_conv_k<<<dim3(D_MODEL / 32, D_MODEL / 32, 1), 256, 0, stream>>>(Wo, Wot, D_MODEL, D_MODEL);
  proj_gemm_k<<<dim3(S_LEN / 128, D_MODEL / 128, 3), 256, 0, stream>>>(
      QKVb, Wqt, Wkt, Wvt, bq, bk, bv, qbuf, kbuf, vTb);
  attn_k<<<dim3(S_LEN / 64, NH), 512, 0, stream>>>(qbuf, kbuf, vTb, conc);
  out_gemm_k<<<dim3(D_MODEL / 64, S_LEN / 64), 256, 0, stream>>>(conc, Wot, bo, out);
}

// Round 7
// 175.128 us; speedup vs baseline: 1.1817x; 1.1817x over previous
//
#include <hip/hip_runtime.h>
#include <stdint.h>

#define S_LEN 2048
#define D_MODEL 1024
#define NH 16
#define DKV 64

typedef unsigned short u16;
typedef __bf16 bf16x8 __attribute__((ext_vector_type(8)));
typedef float f32x4 __attribute__((ext_vector_type(4)));

__device__ __forceinline__ u16 f2bf(float f) {
  union { float f; uint32_t u; } v; v.f = f;
  uint32_t r = v.u + 0x7FFFu + ((v.u >> 16) & 1u);
  return (u16)(r >> 16);
}
// pack two positive floats to bf16x2 (cheap round; softmax-normalized later)
__device__ __forceinline__ uint32_t pkbf(float lo, float hi) {
  union { float f; uint32_t u; } a, b; a.f = lo; b.f = hi;
  return ((b.u + 0x8000u) & 0xFFFF0000u) | ((a.u + 0x8000u) >> 16);
}
// async global->LDS 16B: per-wave, dest = wave-uniform base + lane*16
__device__ __forceinline__ void gl16(const u16* g, u16* l) {
  __builtin_amdgcn_global_load_lds(
      (const __attribute__((address_space(1))) unsigned int*)g,
      (__attribute__((address_space(3))) unsigned int*)l, 16, 0, 0);
}

// ---------- convert Q,K,V fp32 -> bf16 ----------
__global__ __launch_bounds__(256) void conv_qkv_k(
    const float* __restrict__ Q, const float* __restrict__ K,
    const float* __restrict__ V, u16* __restrict__ out) {
  const float* src = (blockIdx.z == 0) ? Q : (blockIdx.z == 1) ? K : V;
  u16* dst = out + (size_t)blockIdx.z * S_LEN * D_MODEL;
  size_t i = ((size_t)blockIdx.x * blockDim.x + threadIdx.x) * 4;
  const float4 v = *(const float4*)(src + i);
  union { u16 h[4]; uint2 u2; } o;
  o.h[0] = f2bf(v.x); o.h[1] = f2bf(v.y); o.h[2] = f2bf(v.z); o.h[3] = f2bf(v.w);
  *(uint2*)(dst + i) = o.u2;
}

// ---------- transpose+convert Wq/Wk/Wv: [D][DK] -> [DK][D] per head ----------
__global__ __launch_bounds__(256) void transpose_qkvw_k(
    const float* __restrict__ Wq, const float* __restrict__ Wk,
    const float* __restrict__ Wv, u16* __restrict__ Wqt,
    u16* __restrict__ Wkt, u16* __restrict__ Wvt) {
  __shared__ float tile[32][33];
  const int which = blockIdx.z >> 4, head = blockIdx.z & 15;
  const float* ip = ((which == 0) ? Wq : (which == 1) ? Wk : Wv) + (size_t)head * D_MODEL * DKV;
  u16* op = ((which == 0) ? Wqt : (which == 1) ? Wkt : Wvt) + (size_t)head * D_MODEL * DKV;
  int r0 = blockIdx.y * 32, c0 = blockIdx.x * 32;
  int tr = threadIdx.x >> 5, tc = threadIdx.x & 31;
#pragma unroll
  for (int i = 0; i < 4; i++)
    tile[tr + i * 8][tc] = ip[(size_t)(r0 + tr + i * 8) * DKV + c0 + tc];
  __syncthreads();
#pragma unroll
  for (int i = 0; i < 4; i++) {
    int c = tr + i * 8;
    op[(size_t)(c0 + c) * D_MODEL + r0 + tc] = f2bf(tile[tc][c]);
  }
}

// ---------- transpose + convert generic (Wo): fp32 [R][C] -> bf16 [C][R] ----------
__global__ __launch_bounds__(256) void transpose_conv_k(
    const float* __restrict__ in, u16* __restrict__ out, int R, int C) {
  __shared__ float tile[32][33];
  int r0 = blockIdx.y * 32, c0 = blockIdx.x * 32;
  int tr = threadIdx.x >> 5, tc = threadIdx.x & 31;
#pragma unroll
  for (int i = 0; i < 4; i++)
    tile[tr + i * 8][tc] = in[(size_t)(r0 + tr + i * 8) * C + c0 + tc];
  __syncthreads();
#pragma unroll
  for (int i = 0; i < 4; i++) {
    int c = tr + i * 8;
    out[(size_t)(c0 + c) * R + r0 + tc] = f2bf(tile[tc][c]);
  }
}

// ---------- projection GEMM m97-style: 128x128 tile, BK=64, async dbuf, 1 barrier/iter ----------
__global__ __launch_bounds__(256, 2) void proj_gemm_k(
    const u16* __restrict__ qkvb, const u16* __restrict__ Wqt,
    const u16* __restrict__ Wkt, const u16* __restrict__ Wvt,
    const float* __restrict__ bq, const float* __restrict__ bk,
    const float* __restrict__ bv,
    u16* __restrict__ qb, u16* __restrict__ kb, u16* __restrict__ vT) {
  const int z = blockIdx.z;
  const int m0 = blockIdx.x * 128, n0 = blockIdx.y * 128;
  const u16* A = qkvb + (size_t)z * S_LEN * D_MODEL;
  const u16* Bt = (z == 0) ? Wqt : (z == 1) ? Wkt : Wvt;
  const float* bias = (z == 0) ? bq : (z == 1) ? bk : bv;
  const float scale = (z == 0) ? 0.18033688f : 1.0f;  // (1/8)*log2(e) folded into q

  __shared__ __align__(16) u16 smem[4 * 8192];  // A0 A1 B0 B1 (16KB each)
  const int tid = threadIdx.x;
  const int w = tid >> 6, lane = tid & 63, quad = lane >> 4, l15 = lane & 15;
  const int wm = (w >> 1) * 64, wn = (w & 1) * 64;
  const int pb = w * 256;

  f32x4 acc[4][4] = {};

  {
    u16* As = smem; u16* Bs = smem + 16384;
#pragma unroll
    for (int e = 0; e < 4; e++) {
      int p = pb + e * 64 + lane;
      int r = p >> 3, cg = (p & 7) ^ (r & 7);
      gl16(&A[(size_t)(m0 + r) * D_MODEL + cg * 8], As + (pb + e * 64) * 8);
      gl16(&Bt[(size_t)(n0 + r) * D_MODEL + cg * 8], Bs + (pb + e * 64) * 8);
    }
  }
  for (int it = 0; it < 16; it++) {
    __syncthreads();
    if (it < 15) {
      const int k0 = (it + 1) * 64;
      u16* As = smem + ((it + 1) & 1) * 8192;
      u16* Bs = smem + 16384 + ((it + 1) & 1) * 8192;
#pragma unroll
      for (int e = 0; e < 4; e++) {
        int p = pb + e * 64 + lane;
        int r = p >> 3, cg = (p & 7) ^ (r & 7);
        gl16(&A[(size_t)(m0 + r) * D_MODEL + k0 + cg * 8], As + (pb + e * 64) * 8);
        gl16(&Bt[(size_t)(n0 + r) * D_MODEL + k0 + cg * 8], Bs + (pb + e * 64) * 8);
      }
    }
    const u16* As = smem + (it & 1) * 8192;
    const u16* Bs = smem + 16384 + (it & 1) * 8192;
#pragma unroll
    for (int kc = 0; kc < 2; kc++) {
      bf16x8 af[4], bfr[4];
      const int c = kc * 4 + quad;
#pragma unroll
      for (int t = 0; t < 4; t++) {
        int ma = wm + t * 16 + l15, na = wn + t * 16 + l15;
        af[t] = *(const bf16x8*)&As[(ma * 8 + (c ^ (ma & 7))) * 8];
        bfr[t] = *(const bf16x8*)&Bs[(na * 8 + (c ^ (na & 7))) * 8];
      }
#pragma unroll
      for (int tm = 0; tm < 4; tm++)
#pragma unroll
        for (int tn = 0; tn < 4; tn++)
          acc[tm][tn] = __builtin_amdgcn_mfma_f32_16x16x32_bf16(af[tm], bfr[tn], acc[tm][tn], 0, 0, 0);
    }
  }

  if (z < 2) {
    u16* O = (z == 0) ? qb : kb;
#pragma unroll
    for (int tm = 0; tm < 4; tm++)
#pragma unroll
      for (int tn = 0; tn < 4; tn++)
#pragma unroll
        for (int r = 0; r < 4; r++) {
          int row = m0 + wm + tm * 16 + quad * 4 + r;
          int col = n0 + wn + tn * 16 + l15;
          O[(size_t)row * D_MODEL + col] = f2bf((acc[tm][tn][r] + bias[col]) * scale);
        }
  } else {
#pragma unroll
    for (int tm = 0; tm < 4; tm++)
#pragma unroll
      for (int tn = 0; tn < 4; tn++) {
        int col = n0 + wn + tn * 16 + l15;
        int row0 = m0 + wm + tm * 16 + quad * 4;
        float b = bias[col];
        union { u16 h[4]; uint2 u2; } o;
#pragma unroll
        for (int r = 0; r < 4; r++) o.h[r] = f2bf(acc[tm][tn][r] + b);
        *(uint2*)&vT[(size_t)col * S_LEN + row0] = o.u2;
      }
  }
}

// ---------- attention: round-4 structure (16x16x32, high-ILP chains) + XOR-swizzled K/V ----------
// 512 thr = 8 waves = {4 q-subs(16q)} x {2 KV halves}; q-tile 64; t-tiles of 64.
// LDS chunk slot for (row r, 16B chunk c) = c ^ (r&7): conflict-free b128 frag reads,
// sequential staging writes, full-row coalesced global reads. P strip keeps stride-72 pad.
__global__ __launch_bounds__(512) void attn_k(
    const u16* __restrict__ qb, const u16* __restrict__ kb,
    const u16* __restrict__ vT, u16* __restrict__ conc) {
  const int h = blockIdx.y, qblk = blockIdx.x * 64;
  const int tid = threadIdx.x;
  const int w = tid >> 6, lane = tid & 63, quad = lane >> 4, l15 = lane & 15;
  const int half = w >> 2, wq = w & 3;
  const int q0 = qblk + wq * 16;

  // u16 layout: K[2][64][8ch] @0 (16KB), V[2][64][8ch] @8192 (16KB), P[8][16][72] @16384 (18KB)
  // epilogue overlays @0 as float Osh[8][16][68] + lsh[8][16] (35.3KB < 50KB)
  __shared__ __align__(16) u16 smem[25600];
  u16* Kh = smem + half * 4096;
  u16* Vh = smem + 8192 + half * 4096;
  u16* Pw = smem + 16384 + w * 1152;

  // Q B-frags (n=q=l15, k=dk=kc*32+quad*8+j); q pre-scaled by (1/8)*log2(e)
  bf16x8 qf[2];
#pragma unroll
  for (int kc = 0; kc < 2; kc++)
    qf[kc] = *(const bf16x8*)&qb[(size_t)(q0 + l15) * D_MODEL + h * 64 + kc * 32 + quad * 8];

  const int gi = tid & 255;
  const u16* kbase = kb + (size_t)h * 64;
  const u16* vbase = vT + (size_t)(h * 64) * S_LEN;

  f32x4 oacc[4] = {};
  float lsum = 0.f;

  for (int it = 0; it < 16; it++) {
    const int t0 = half * 1024 + it * 64;
    // each 256-thread half-group stages its half's K (natural rows) and Vᵀ rows, swizzled
#pragma unroll
    for (int j = 0; j < 2; j++) {
      int p = j * 256 + gi;  // 512 16B-chunks per array per half
      int r = p >> 3, cg = (p & 7) ^ (r & 7);
      *(int4*)&Kh[p * 8] = *(const int4*)&kbase[(size_t)(t0 + r) * D_MODEL + cg * 8];
      *(int4*)&Vh[p * 8] = *(const int4*)&vbase[(size_t)r * S_LEN + t0 + cg * 8];
    }
    __syncthreads();

    // Sᵀ = K·Qᵀ : 4 independent accumulation chains (tn), depth 2 (kc)
    f32x4 sacc[4] = {};
#pragma unroll
    for (int kc = 0; kc < 2; kc++)
#pragma unroll
      for (int tn = 0; tn < 4; tn++) {
        int rr = tn * 16 + l15;
        bf16x8 ka = *(const bf16x8*)&Kh[(rr * 8 + ((kc * 4 + quad) ^ (l15 & 7))) * 8];
        sacc[tn] = __builtin_amdgcn_mfma_f32_16x16x32_bf16(ka, qf[kc], sacc[tn], 0, 0, 0);
      }

    // p = 2^s (log2e folded into q); lane holds Sᵀ[t=tn*16+quad*4+r][q=l15]
    // -> 4 consecutive t: packed b64 write into wave-private P strip [q][t]
#pragma unroll
    for (int tn = 0; tn < 4; tn++) {
      float p0 = exp2f(sacc[tn][0]);
      float p1 = exp2f(sacc[tn][1]);
      float p2 = exp2f(sacc[tn][2]);
      float p3 = exp2f(sacc[tn][3]);
      lsum += (p0 + p1) + (p2 + p3);
      uint2 pw2; pw2.x = pkbf(p0, p1); pw2.y = pkbf(p2, p3);
      *(uint2*)&Pw[l15 * 72 + tn * 16 + quad * 4] = pw2;
    }

    // O += P·V : 4 independent chains (nt), depth 2 (kb2)
#pragma unroll
    for (int kb2 = 0; kb2 < 2; kb2++) {
      bf16x8 pa = *(const bf16x8*)&Pw[l15 * 72 + kb2 * 32 + quad * 8];
#pragma unroll
      for (int nt = 0; nt < 4; nt++) {
        int rr = nt * 16 + l15;
        bf16x8 vb = *(const bf16x8*)&Vh[(rr * 8 + ((kb2 * 4 + quad) ^ (l15 & 7))) * 8];
        oacc[nt] = __builtin_amdgcn_mfma_f32_16x16x32_bf16(pa, vb, oacc[nt], 0, 0, 0);
      }
    }
    __syncthreads();
  }

  // reduce lsum over quads (lane's lsum is for q=l15)
  lsum += __shfl_xor(lsum, 16, 64);
  lsum += __shfl_xor(lsum, 32, 64);

  float* OshF = (float*)smem;          // [8][16][68]
  float* lshF = OshF + 8 * 16 * 68;    // [8][16]
  if (lane < 16) lshF[w * 16 + lane] = lsum;
#pragma unroll
  for (int nt = 0; nt < 4; nt++)
#pragma unroll
    for (int r = 0; r < 4; r++)
      OshF[w * 1088 + (quad * 4 + r) * 68 + nt * 16 + l15] = oacc[nt][r];
  __syncthreads();

  // combine the two KV halves, normalize, write concat (bf16)
  const int q = tid >> 3;            // 0..63
  const int dv0 = (tid & 7) * 8;
  const int wa = q >> 4, wb = wa + 4, qr = q & 15;
  const float* pa = &OshF[wa * 1088 + qr * 68 + dv0];
  const float* pb = &OshF[wb * 1088 + qr * 68 + dv0];
  float4 a0 = *(const float4*)pa, a1 = *(const float4*)(pa + 4);
  float4 b0 = *(const float4*)pb, b1 = *(const float4*)(pb + 4);
  float li = 1.0f / (lshF[wa * 16 + qr] + lshF[wb * 16 + qr]);
  union { u16 hh[8]; uint4 u4; } o;
  o.hh[0] = f2bf((a0.x + b0.x) * li); o.hh[1] = f2bf((a0.y + b0.y) * li);
  o.hh[2] = f2bf((a0.z + b0.z) * li); o.hh[3] = f2bf((a0.w + b0.w) * li);
  o.hh[4] = f2bf((a1.x + b1.x) * li); o.hh[5] = f2bf((a1.y + b1.y) * li);
  o.hh[6] = f2bf((a1.z + b1.z) * li); o.hh[7] = f2bf((a1.w + b1.w) * li);
  *(uint4*)&conc[(size_t)(qblk + q) * D_MODEL + h * 64 + dv0] = o.u4;
}

// ---------- output GEMM: 64x64 tile, BK=64, async dbuf, 1 barrier/iter ----------
__global__ __launch_bounds__(256, 4) void out_gemm_k(
    const u16* __restrict__ A, const u16* __restrict__ Bt,
    const float* __restrict__ bias, float* __restrict__ out) {
  const int n0 = blockIdx.x * 64, m0 = blockIdx.y * 64;
  __shared__ __align__(16) u16 smem[4 * 4096];  // A0 A1 B0 B1 (8KB each)
  const int tid = threadIdx.x;
  const int w = tid >> 6, lane = tid & 63, quad = lane >> 4, l15 = lane & 15;
  const int wm = (w >> 1) * 32, wn = (w & 1) * 32;
  const int pb = w * 128;

  f32x4 acc[2][2] = {};
  {
    u16* As = smem; u16* Bs = smem + 8192;
#pragma unroll
    for (int e = 0; e < 2; e++) {
      int p = pb + e * 64 + lane;
      int r = p >> 3, cg = (p & 7) ^ (r & 7);
      gl16(&A[(size_t)(m0 + r) * D_MODEL + cg * 8], As + (pb + e * 64) * 8);
      gl16(&Bt[(size_t)(n0 + r) * D_MODEL + cg * 8], Bs + (pb + e * 64) * 8);
    }
  }
  for (int it = 0; it < 16; it++) {
    __syncthreads();
    if (it < 15) {
      const int k0 = (it + 1) * 64;
      u16* As = smem + ((it + 1) & 1) * 4096;
      u16* Bs = smem + 8192 + ((it + 1) & 1) * 4096;
#pragma unroll
      for (int e = 0; e < 2; e++) {
        int p = pb + e * 64 + lane;
        int r = p >> 3, cg = (p & 7) ^ (r & 7);
        gl16(&A[(size_t)(m0 + r) * D_MODEL + k0 + cg * 8], As + (pb + e * 64) * 8);
        gl16(&Bt[(size_t)(n0 + r) * D_MODEL + k0 + cg * 8], Bs + (pb + e * 64) * 8);
      }
    }
    const u16* As = smem + (it & 1) * 4096;
    const u16* Bs = smem + 8192 + (it & 1) * 4096;
#pragma unroll
    for (int kc = 0; kc < 2; kc++) {
      const int c = kc * 4 + quad;
      bf16x8 af[2], bfr[2];
#pragma unroll
      for (int t = 0; t < 2; t++) {
        int ma = wm + t * 16 + l15, na = wn + t * 16 + l15;
        af[t] = *(const bf16x8*)&As[(ma * 8 + (c ^ (ma & 7))) * 8];
        bfr[t] = *(const bf16x8*)&Bs[(na * 8 + (c ^ (na & 7))) * 8];
      }
#pragma unroll
      for (int tm = 0; tm < 2; tm++)
#pragma unroll
        for (int tn = 0; tn < 2; tn++)
          acc[tm][tn] = __builtin_amdgcn_mfma_f32_16x16x32_bf16(af[tm], bfr[tn], acc[tm][tn], 0, 0, 0);
    }
  }
#pragma unroll
  for (int tm = 0; tm < 2; tm++)
#pragma unroll
    for (int tn = 0; tn < 2; tn++)
#pragma unroll
      for (int r = 0; r < 4; r++) {
        int row = m0 + wm + tm * 16 + quad * 4 + r;
        int col = n0 + wn + tn * 16 + l15;
        out[(size_t)row * D_MODEL + col] = acc[tm][tn][r] + bias[col];
      }
}

extern "C" void kernel_launch(void* const* d_in, const int* in_sizes, int n_in,
                              void* d_out, int out_size, void* d_ws, size_t ws_size,
                              hipStream_t stream) {
  const float* Q  = (const float*)d_in[0];
  const float* K  = (const float*)d_in[1];
  const float* V  = (const float*)d_in[2];
  const float* Wq = (const float*)d_in[3];
  const float* bq = (const float*)d_in[4];
  const float* Wk = (const float*)d_in[5];
  const float* bk = (const float*)d_in[6];
  const float* Wv = (const float*)d_in[7];
  const float* bv = (const float*)d_in[8];
  const float* Wo = (const float*)d_in[9];
  const float* bo = (const float*)d_in[10];
  float* out = (float*)d_out;

  u16* ws = (u16*)d_ws;
  u16* QKVb = ws;                                   // 3*S*D
  u16* Wqt  = QKVb + (size_t)3 * S_LEN * D_MODEL;   // D*D each
  u16* Wkt  = Wqt + (size_t)D_MODEL * D_MODEL;
  u16* Wvt  = Wkt + (size_t)D_MODEL * D_MODEL;
  u16* Wot  = Wvt + (size_t)D_MODEL * D_MODEL;
  u16* qbuf = Wot + (size_t)D_MODEL * D_MODEL;      // S*D
  u16* kbuf = qbuf + (size_t)S_LEN * D_MODEL;       // S*D
  u16* vTb  = kbuf + (size_t)S_LEN * D_MODEL;       // D*S
  u16* conc = vTb + (size_t)S_LEN * D_MODEL;        // S*D

  conv_qkv_k<<<dim3(S_LEN * D_MODEL / 1024, 1, 3), 256, 0, stream>>>(Q, K, V, QKVb);
  transpose_qkvw_k<<<dim3(DKV / 32, D_MODEL / 32, NH * 3), 256, 0, stream>>>(
      Wq, Wk, Wv, Wqt, Wkt, Wvt);
  transpose_conv_k<<<dim3(D_MODEL / 32, D_MODEL / 32, 1), 256, 0, stream>>>(Wo, Wot, D_MODEL, D_MODEL);
  proj_gemm_k<<<dim3(S_LEN / 128, D_MODEL / 128, 3), 256, 0, stream>>>(
      QKVb, Wqt, Wkt, Wvt, bq, bk, bv, qbuf, kbuf, vTb);
  attn_k<<<dim3(S_LEN / 64, NH), 512, 0, stream>>>(qbuf, kbuf, vTb, conc);
  out_gemm_k<<<dim3(D_MODEL / 64, S_LEN / 64), 256, 0, stream>>>(conc, Wot, bo, out);
}

// Round 8
// 164.779 us; speedup vs baseline: 1.2560x; 1.0628x over previous
//
#include <hip/hip_runtime.h>
#include <stdint.h>

#define S_LEN 2048
#define D_MODEL 1024
#define NH 16
#define DKV 64

typedef unsigned short u16;
typedef __bf16 bf16x8 __attribute__((ext_vector_type(8)));
typedef float f32x4 __attribute__((ext_vector_type(4)));

__device__ __forceinline__ u16 f2bf(float f) {
  union { float f; uint32_t u; } v; v.f = f;
  uint32_t r = v.u + 0x7FFFu + ((v.u >> 16) & 1u);
  return (u16)(r >> 16);
}
// pack two positive floats to bf16x2 (cheap round; softmax-normalized later)
__device__ __forceinline__ uint32_t pkbf(float lo, float hi) {
  union { float f; uint32_t u; } a, b; a.f = lo; b.f = hi;
  return ((b.u + 0x8000u) & 0xFFFF0000u) | ((a.u + 0x8000u) >> 16);
}
// async global->LDS 16B: lds dest is WAVE-UNIFORM base; HW adds lane*16
__device__ __forceinline__ void gl16(const u16* g, u16* l) {
  __builtin_amdgcn_global_load_lds(
      (const __attribute__((address_space(1))) unsigned int*)g,
      (__attribute__((address_space(3))) unsigned int*)l, 16, 0, 0);
}

// ---------- fused preprocessing: conv QKV + transpose Wq/Wk/Wv + transpose Wo ----------
// 1D grid: [0,6144) conv, [6144,9216) qkvw transpose, [9216,10240) Wo transpose
__global__ __launch_bounds__(256) void prep_k(
    const float* __restrict__ Q, const float* __restrict__ K,
    const float* __restrict__ V, const float* __restrict__ Wq,
    const float* __restrict__ Wk, const float* __restrict__ Wv,
    const float* __restrict__ Wo, u16* __restrict__ QKVb,
    u16* __restrict__ Wqt, u16* __restrict__ Wkt, u16* __restrict__ Wvt,
    u16* __restrict__ Wot) {
  __shared__ float tile[32][33];
  const int idx = blockIdx.x;
  if (idx < 6144) {
    const int z = idx >> 11, blk = idx & 2047;
    const float* src = (z == 0) ? Q : (z == 1) ? K : V;
    u16* dst = QKVb + (size_t)z * S_LEN * D_MODEL;
    size_t i = ((size_t)blk * 256 + threadIdx.x) * 4;
    const float4 v = *(const float4*)(src + i);
    union { u16 h[4]; uint2 u2; } o;
    o.h[0] = f2bf(v.x); o.h[1] = f2bf(v.y); o.h[2] = f2bf(v.z); o.h[3] = f2bf(v.w);
    *(uint2*)(dst + i) = o.u2;
    return;
  }
  const float* ip; u16* op; int R, C, r0, c0;
  if (idx < 9216) {
    int t = idx - 6144;
    int which = t >> 10, head = (t & 1023) >> 6, tl = t & 63;
    ip = ((which == 0) ? Wq : (which == 1) ? Wk : Wv) + (size_t)head * D_MODEL * DKV;
    op = ((which == 0) ? Wqt : (which == 1) ? Wkt : Wvt) + (size_t)head * D_MODEL * DKV;
    R = D_MODEL; C = DKV; c0 = (tl & 1) * 32; r0 = (tl >> 1) * 32;
  } else {
    int t = idx - 9216;
    ip = Wo; op = Wot; R = D_MODEL; C = D_MODEL;
    c0 = (t & 31) * 32; r0 = (t >> 5) * 32;
  }
  int tr = threadIdx.x >> 5, tc = threadIdx.x & 31;
#pragma unroll
  for (int i = 0; i < 4; i++)
    tile[tr + i * 8][tc] = ip[(size_t)(r0 + tr + i * 8) * C + c0 + tc];
  __syncthreads();
#pragma unroll
  for (int i = 0; i < 4; i++) {
    int c = tr + i * 8;
    op[(size_t)(c0 + c) * R + r0 + tc] = f2bf(tile[tc][c]);
  }
}

// ---------- projection GEMM m97-style: 128x128 tile, BK=64, async dbuf, 1 barrier/iter ----------
__global__ __launch_bounds__(256, 2) void proj_gemm_k(
    const u16* __restrict__ qkvb, const u16* __restrict__ Wqt,
    const u16* __restrict__ Wkt, const u16* __restrict__ Wvt,
    const float* __restrict__ bq, const float* __restrict__ bk,
    const float* __restrict__ bv,
    u16* __restrict__ qb, u16* __restrict__ kb, u16* __restrict__ vT) {
  const int z = blockIdx.z;
  const int m0 = blockIdx.x * 128, n0 = blockIdx.y * 128;
  const u16* A = qkvb + (size_t)z * S_LEN * D_MODEL;
  const u16* Bt = (z == 0) ? Wqt : (z == 1) ? Wkt : Wvt;
  const float* bias = (z == 0) ? bq : (z == 1) ? bk : bv;
  const float scale = (z == 0) ? 0.18033688f : 1.0f;  // (1/8)*log2(e) folded into q

  __shared__ __align__(16) u16 smem[4 * 8192];  // A0 A1 B0 B1 (16KB each)
  const int tid = threadIdx.x;
  const int w = tid >> 6, lane = tid & 63, quad = lane >> 4, l15 = lane & 15;
  const int wm = (w >> 1) * 64, wn = (w & 1) * 64;
  const int pb = w * 256;

  f32x4 acc[4][4] = {};

  {
    u16* As = smem; u16* Bs = smem + 16384;
#pragma unroll
    for (int e = 0; e < 4; e++) {
      int p = pb + e * 64 + lane;
      int r = p >> 3, cg = (p & 7) ^ (r & 7);
      gl16(&A[(size_t)(m0 + r) * D_MODEL + cg * 8], As + (pb + e * 64) * 8);
      gl16(&Bt[(size_t)(n0 + r) * D_MODEL + cg * 8], Bs + (pb + e * 64) * 8);
    }
  }
  for (int it = 0; it < 16; it++) {
    __syncthreads();
    if (it < 15) {
      const int k0 = (it + 1) * 64;
      u16* As = smem + ((it + 1) & 1) * 8192;
      u16* Bs = smem + 16384 + ((it + 1) & 1) * 8192;
#pragma unroll
      for (int e = 0; e < 4; e++) {
        int p = pb + e * 64 + lane;
        int r = p >> 3, cg = (p & 7) ^ (r & 7);
        gl16(&A[(size_t)(m0 + r) * D_MODEL + k0 + cg * 8], As + (pb + e * 64) * 8);
        gl16(&Bt[(size_t)(n0 + r) * D_MODEL + k0 + cg * 8], Bs + (pb + e * 64) * 8);
      }
    }
    const u16* As = smem + (it & 1) * 8192;
    const u16* Bs = smem + 16384 + (it & 1) * 8192;
#pragma unroll
    for (int kc = 0; kc < 2; kc++) {
      bf16x8 af[4], bfr[4];
      const int c = kc * 4 + quad;
#pragma unroll
      for (int t = 0; t < 4; t++) {
        int ma = wm + t * 16 + l15, na = wn + t * 16 + l15;
        af[t] = *(const bf16x8*)&As[(ma * 8 + (c ^ (ma & 7))) * 8];
        bfr[t] = *(const bf16x8*)&Bs[(na * 8 + (c ^ (na & 7))) * 8];
      }
#pragma unroll
      for (int tm = 0; tm < 4; tm++)
#pragma unroll
        for (int tn = 0; tn < 4; tn++)
          acc[tm][tn] = __builtin_amdgcn_mfma_f32_16x16x32_bf16(af[tm], bfr[tn], acc[tm][tn], 0, 0, 0);
    }
  }

  if (z < 2) {
    u16* O = (z == 0) ? qb : kb;
#pragma unroll
    for (int tm = 0; tm < 4; tm++)
#pragma unroll
      for (int tn = 0; tn < 4; tn++)
#pragma unroll
        for (int r = 0; r < 4; r++) {
          int row = m0 + wm + tm * 16 + quad * 4 + r;
          int col = n0 + wn + tn * 16 + l15;
          O[(size_t)row * D_MODEL + col] = f2bf((acc[tm][tn][r] + bias[col]) * scale);
        }
  } else {
#pragma unroll
    for (int tm = 0; tm < 4; tm++)
#pragma unroll
      for (int tn = 0; tn < 4; tn++) {
        int col = n0 + wn + tn * 16 + l15;
        int row0 = m0 + wm + tm * 16 + quad * 4;
        float b = bias[col];
        union { u16 h[4]; uint2 u2; } o;
#pragma unroll
        for (int r = 0; r < 4; r++) o.h[r] = f2bf(acc[tm][tn][r] + b);
        *(uint2*)&vT[(size_t)col * S_LEN + row0] = o.u2;
      }
  }
}

// ---------- attention: gl16 async dbuf K/V, single barrier/iter, 16x16 high-ILP body ----------
// 512 thr = 8 waves = {4 q-subs(16q)} x {2 KV halves}; q-tile 64; t-tile 32/iter, 32 iters.
// K chunks slot = c ^ (r&7); V chunks slot = c ^ (dv&3); P strip [16][72] per wave.
__global__ __launch_bounds__(512) void attn_k(
    const u16* __restrict__ qb, const u16* __restrict__ kb,
    const u16* __restrict__ vT, u16* __restrict__ conc) {
  const int h = blockIdx.y, qblk = blockIdx.x * 64;
  const int tid = threadIdx.x;
  const int w = tid >> 6, lane = tid & 63, quad = lane >> 4, l15 = lane & 15;
  const int half = w >> 2, wq = w & 3;
  const int q0 = qblk + wq * 16;

  // u16: K[2 half][2 buf][256ch] @0 (16KB), V[2][2][256ch] @8192 (16KB), P[8][16*72] @16384 (18KB)
  // epilogue overlays @0 as float Osh[8][16][68] + lsh[8][16] (35.3KB < 50KB)
  __shared__ __align__(16) u16 smem[25600];
  u16* Kh = smem + half * 4096;
  u16* Vh = smem + 8192 + half * 4096;
  u16* Pw = smem + 16384 + w * 1152;

  // Q B-frags (n=q=l15, k=dk=kc*32+quad*8+j); q pre-scaled by (1/8)*log2(e)
  bf16x8 qf[2];
#pragma unroll
  for (int kc = 0; kc < 2; kc++)
    qf[kc] = *(const bf16x8*)&qb[(size_t)(q0 + l15) * D_MODEL + h * 64 + kc * 32 + quad * 8];

  const u16* kbase = kb + (size_t)h * 64;
  const u16* vbase = vT + (size_t)(h * 64) * S_LEN;

  // per-wave staging: 1 K chunk + 1 V chunk per lane per iter
  const int p = wq * 64 + lane;                   // 0..255
  const int kr = p >> 3, kcg = (p & 7) ^ (kr & 7);
  const int vr = p >> 2, vcg = (p & 3) ^ (vr & 3);
  const size_t kgoff = (size_t)kr * D_MODEL + kcg * 8;
  const size_t vgoff = (size_t)vr * S_LEN + vcg * 8;
  const int ldsoff = wq * 64 * 8;                 // wave-uniform dest (HW adds lane*16)

  f32x4 oacc[4] = {};
  float lsum = 0.f;

  {  // preload it=0 into buf0
    const int t0 = half * 1024;
    gl16(kbase + (size_t)t0 * D_MODEL + kgoff, Kh + ldsoff);
    gl16(vbase + t0 + vgoff, Vh + ldsoff);
  }

  for (int it = 0; it < 32; it++) {
    __syncthreads();  // buf[it&1] staged (compiler drains vmcnt before barrier)
    if (it < 31) {    // prefetch buf[(it+1)&1]; stays in flight across this compute
      const int t0n = half * 1024 + (it + 1) * 32;
      u16* Kd = Kh + ((it + 1) & 1) * 2048;
      u16* Vd = Vh + ((it + 1) & 1) * 2048;
      gl16(kbase + (size_t)t0n * D_MODEL + kgoff, Kd + ldsoff);
      gl16(vbase + t0n + vgoff, Vd + ldsoff);
    }
    const u16* Kc = Kh + (it & 1) * 2048;
    const u16* Vc = Vh + (it & 1) * 2048;

    // Sᵀ = K·Qᵀ : 2 independent chains (tn), depth 2 (kc)
    f32x4 sacc[2] = {};
#pragma unroll
    for (int kc = 0; kc < 2; kc++)
#pragma unroll
      for (int tn = 0; tn < 2; tn++) {
        int rr = tn * 16 + l15;
        bf16x8 ka = *(const bf16x8*)&Kc[(rr * 8 + ((kc * 4 + quad) ^ (rr & 7))) * 8];
        sacc[tn] = __builtin_amdgcn_mfma_f32_16x16x32_bf16(ka, qf[kc], sacc[tn], 0, 0, 0);
      }

    // p = 2^s (log2e folded into q); lane holds Sᵀ[t=tn*16+quad*4+r][q=l15]
#pragma unroll
    for (int tn = 0; tn < 2; tn++) {
      float p0 = exp2f(sacc[tn][0]);
      float p1 = exp2f(sacc[tn][1]);
      float p2 = exp2f(sacc[tn][2]);
      float p3 = exp2f(sacc[tn][3]);
      lsum += (p0 + p1) + (p2 + p3);
      uint2 pw2; pw2.x = pkbf(p0, p1); pw2.y = pkbf(p2, p3);
      *(uint2*)&Pw[l15 * 72 + tn * 16 + quad * 4] = pw2;
    }

    // O += P·V : 4 fully independent chains (nt), k=32 (one MFMA each)
    bf16x8 pa = *(const bf16x8*)&Pw[l15 * 72 + quad * 8];
#pragma unroll
    for (int nt = 0; nt < 4; nt++) {
      int dv = nt * 16 + l15;
      bf16x8 vb = *(const bf16x8*)&Vc[(dv * 4 + (quad ^ (dv & 3))) * 8];
      oacc[nt] = __builtin_amdgcn_mfma_f32_16x16x32_bf16(pa, vb, oacc[nt], 0, 0, 0);
    }
  }
  __syncthreads();  // all waves done with K/V buffers before overlay

  // reduce lsum over quads (lane's lsum is for q=l15)
  lsum += __shfl_xor(lsum, 16, 64);
  lsum += __shfl_xor(lsum, 32, 64);

  float* OshF = (float*)smem;          // [8][16][68]
  float* lshF = OshF + 8 * 16 * 68;    // [8][16]
  if (lane < 16) lshF[w * 16 + lane] = lsum;
#pragma unroll
  for (int nt = 0; nt < 4; nt++)
#pragma unroll
    for (int r = 0; r < 4; r++)
      OshF[w * 1088 + (quad * 4 + r) * 68 + nt * 16 + l15] = oacc[nt][r];
  __syncthreads();

  // combine the two KV halves, normalize, write concat (bf16)
  const int q = tid >> 3;            // 0..63
  const int dv0 = (tid & 7) * 8;
  const int wa = q >> 4, wb = wa + 4, qr = q & 15;
  const float* pa = &OshF[wa * 1088 + qr * 68 + dv0];
  const float* pb = &OshF[wb * 1088 + qr * 68 + dv0];
  float4 a0 = *(const float4*)pa, a1 = *(const float4*)(pa + 4);
  float4 b0 = *(const float4*)pb, b1 = *(const float4*)(pb + 4);
  float li = 1.0f / (lshF[wa * 16 + qr] + lshF[wb * 16 + qr]);
  union { u16 hh[8]; uint4 u4; } o;
  o.hh[0] = f2bf((a0.x + b0.x) * li); o.hh[1] = f2bf((a0.y + b0.y) * li);
  o.hh[2] = f2bf((a0.z + b0.z) * li); o.hh[3] = f2bf((a0.w + b0.w) * li);
  o.hh[4] = f2bf((a1.x + b1.x) * li); o.hh[5] = f2bf((a1.y + b1.y) * li);
  o.hh[6] = f2bf((a1.z + b1.z) * li); o.hh[7] = f2bf((a1.w + b1.w) * li);
  *(uint4*)&conc[(size_t)(qblk + q) * D_MODEL + h * 64 + dv0] = o.u4;
}

// ---------- output GEMM: 64x64 tile, BK=64, async dbuf, 1 barrier/iter ----------
__global__ __launch_bounds__(256, 4) void out_gemm_k(
    const u16* __restrict__ A, const u16* __restrict__ Bt,
    const float* __restrict__ bias, float* __restrict__ out) {
  const int n0 = blockIdx.x * 64, m0 = blockIdx.y * 64;
  __shared__ __align__(16) u16 smem[4 * 4096];  // A0 A1 B0 B1 (8KB each)
  const int tid = threadIdx.x;
  const int w = tid >> 6, lane = tid & 63, quad = lane >> 4, l15 = lane & 15;
  const int wm = (w >> 1) * 32, wn = (w & 1) * 32;
  const int pb = w * 128;

  f32x4 acc[2][2] = {};
  {
    u16* As = smem; u16* Bs = smem + 8192;
#pragma unroll
    for (int e = 0; e < 2; e++) {
      int p = pb + e * 64 + lane;
      int r = p >> 3, cg = (p & 7) ^ (r & 7);
      gl16(&A[(size_t)(m0 + r) * D_MODEL + cg * 8], As + (pb + e * 64) * 8);
      gl16(&Bt[(size_t)(n0 + r) * D_MODEL + cg * 8], Bs + (pb + e * 64) * 8);
    }
  }
  for (int it = 0; it < 16; it++) {
    __syncthreads();
    if (it < 15) {
      const int k0 = (it + 1) * 64;
      u16* As = smem + ((it + 1) & 1) * 4096;
      u16* Bs = smem + 8192 + ((it + 1) & 1) * 4096;
#pragma unroll
      for (int e = 0; e < 2; e++) {
        int p = pb + e * 64 + lane;
        int r = p >> 3, cg = (p & 7) ^ (r & 7);
        gl16(&A[(size_t)(m0 + r) * D_MODEL + k0 + cg * 8], As + (pb + e * 64) * 8);
        gl16(&Bt[(size_t)(n0 + r) * D_MODEL + k0 + cg * 8], Bs + (pb + e * 64) * 8);
      }
    }
    const u16* As = smem + (it & 1) * 4096;
    const u16* Bs = smem + 8192 + (it & 1) * 4096;
#pragma unroll
    for (int kc = 0; kc < 2; kc++) {
      const int c = kc * 4 + quad;
      bf16x8 af[2], bfr[2];
#pragma unroll
      for (int t = 0; t < 2; t++) {
        int ma = wm + t * 16 + l15, na = wn + t * 16 + l15;
        af[t] = *(const bf16x8*)&As[(ma * 8 + (c ^ (ma & 7))) * 8];
        bfr[t] = *(const bf16x8*)&Bs[(na * 8 + (c ^ (na & 7))) * 8];
      }
#pragma unroll
      for (int tm = 0; tm < 2; tm++)
#pragma unroll
        for (int tn = 0; tn < 2; tn++)
          acc[tm][tn] = __builtin_amdgcn_mfma_f32_16x16x32_bf16(af[tm], bfr[tn], acc[tm][tn], 0, 0, 0);
    }
  }
#pragma unroll
  for (int tm = 0; tm < 2; tm++)
#pragma unroll
    for (int tn = 0; tn < 2; tn++)
#pragma unroll
      for (int r = 0; r < 4; r++) {
        int row = m0 + wm + tm * 16 + quad * 4 + r;
        int col = n0 + wn + tn * 16 + l15;
        out[(size_t)row * D_MODEL + col] = acc[tm][tn][r] + bias[col];
      }
}

extern "C" void kernel_launch(void* const* d_in, const int* in_sizes, int n_in,
                              void* d_out, int out_size, void* d_ws, size_t ws_size,
                              hipStream_t stream) {
  const float* Q  = (const float*)d_in[0];
  const float* K  = (const float*)d_in[1];
  const float* V  = (const float*)d_in[2];
  const float* Wq = (const float*)d_in[3];
  const float* bq = (const float*)d_in[4];
  const float* Wk = (const float*)d_in[5];
  const float* bk = (const float*)d_in[6];
  const float* Wv = (const float*)d_in[7];
  const float* bv = (const float*)d_in[8];
  const float* Wo = (const float*)d_in[9];
  const float* bo = (const float*)d_in[10];
  float* out = (float*)d_out;

  u16* ws = (u16*)d_ws;
  u16* QKVb = ws;                                   // 3*S*D
  u16* Wqt  = QKVb + (size_t)3 * S_LEN * D_MODEL;   // D*D each
  u16* Wkt  = Wqt + (size_t)D_MODEL * D_MODEL;
  u16* Wvt  = Wkt + (size_t)D_MODEL * D_MODEL;
  u16* Wot  = Wvt + (size_t)D_MODEL * D_MODEL;
  u16* qbuf = Wot + (size_t)D_MODEL * D_MODEL;      // S*D
  u16* kbuf = qbuf + (size_t)S_LEN * D_MODEL;       // S*D
  u16* vTb  = kbuf + (size_t)S_LEN * D_MODEL;       // D*S
  u16* conc = vTb + (size_t)S_LEN * D_MODEL;        // S*D

  prep_k<<<dim3(10240), 256, 0, stream>>>(Q, K, V, Wq, Wk, Wv, Wo,
                                          QKVb, Wqt, Wkt, Wvt, Wot);
  proj_gemm_k<<<dim3(S_LEN / 128, D_MODEL / 128, 3), 256, 0, stream>>>(
      QKVb, Wqt, Wkt, Wvt, bq, bk, bv, qbuf, kbuf, vTb);
  attn_k<<<dim3(S_LEN / 64, NH), 512, 0, stream>>>(qbuf, kbuf, vTb, conc);
  out_gemm_k<<<dim3(D_MODEL / 64, S_LEN / 64), 256, 0, stream>>>(conc, Wot, bo, out);
}